// Round 2
// baseline (3779.820 us; speedup 1.0000x reference)
//
#include <hip/hip_runtime.h>
#include <math.h>

// DAT deformable-attention block, fp32 correctness-first baseline (R2).
// B=4096 windows, H=W=8 (N=64), C=256, NH=8 (hc=32), NG=4 (gc=64), Hk=Wk=4 (ns=16).
//
// R1 bug: o-proj fold used P of the OUTPUT channel's head. Correct contraction:
//   y[d][m] = bo[d] + sum_c wo[d][c] * sum_n P_{head(c)}[m][n] * v[c][n]
// Fixed via per-head fold: voh[h][d][n] = sum_{c in head h} wo[d][c] v[c][n]
// (in VGPRs, thread=d), then y[d][m] = bo[d] + sum_h sum_n P_h[m][n] voh[h][n].
//
// ws layout (floats):
//   wqT @ 0, wkT @ 65536, wvT @ 131072, woT @ 196608   (transposed 256x256 weights)
//   q   @ 262144               (B,256,64) fp32, 268 MB
//   pos @ 67371008             (B,4,16,2) fp32, 2 MB

union F4 { float4 v; float f[4]; };

// ---------------- K0: transpose the four 256x256 weight matrices -------------
__global__ __launch_bounds__(256) void k_transpose4(
    const float* __restrict__ w0, const float* __restrict__ w1,
    const float* __restrict__ w2, const float* __restrict__ w3,
    float* __restrict__ o0, float* __restrict__ o1,
    float* __restrict__ o2, float* __restrict__ o3) {
  int idx = blockIdx.x * 256 + threadIdx.x;   // 0 .. 262143
  int m = idx >> 16;
  int r = idx & 65535;
  int d = r >> 8, c = r & 255;
  const float* w = (m == 0) ? w0 : (m == 1) ? w1 : (m == 2) ? w2 : w3;
  float* o       = (m == 0) ? o0 : (m == 1) ? o1 : (m == 2) ? o2 : o3;
  o[c * 256 + d] = w[r];
}

// ---------------- K1: q = x . Wq^T + bq, stored (b, d, n) --------------------
__global__ __launch_bounds__(256) void k_qproj(
    const float* __restrict__ x, const float* __restrict__ wT,
    const float* __restrict__ bias, float* __restrict__ q) {
  int b = blockIdx.x;
  const float* xb = x + (size_t)b * 16384;
  float* qb = q + (size_t)b * 16384;
  int tid = threadIdx.x;
  int d0 = (tid >> 3) << 3;   // 0..248
  int n0 = (tid & 7) << 3;    // 0..56
  float acc[8][8];
#pragma unroll
  for (int j = 0; j < 8; ++j)
#pragma unroll
    for (int i = 0; i < 8; ++i) acc[j][i] = 0.f;
  for (int c0 = 0; c0 < 256; c0 += 4) {
    F4 bb[8];
#pragma unroll
    for (int i = 0; i < 8; ++i)
      bb[i].v = *(const float4*)(xb + (n0 + i) * 256 + c0);
#pragma unroll
    for (int cc = 0; cc < 4; ++cc) {
      F4 a0, a1;
      a0.v = *(const float4*)(wT + (c0 + cc) * 256 + d0);
      a1.v = *(const float4*)(wT + (c0 + cc) * 256 + d0 + 4);
#pragma unroll
      for (int j = 0; j < 8; ++j) {
        float aj = (j < 4) ? a0.f[j] : a1.f[j - 4];
#pragma unroll
        for (int i = 0; i < 8; ++i)
          acc[j][i] += aj * bb[i].f[cc];
      }
    }
  }
#pragma unroll
  for (int j = 0; j < 8; ++j) {
    float bj = bias[d0 + j];
    F4 o0, o1;
#pragma unroll
    for (int i = 0; i < 4; ++i) { o0.f[i] = acc[j][i] + bj; o1.f[i] = acc[j][i + 4] + bj; }
    *(float4*)(qb + (d0 + j) * 64 + n0) = o0.v;
    *(float4*)(qb + (d0 + j) * 64 + n0 + 4) = o1.v;
  }
}

// ---------------- K2: offset network -> pos (b,g,n,{y,x}) --------------------
__global__ __launch_bounds__(256) void k_offset(
    const float* __restrict__ q, const float* __restrict__ dww,
    const float* __restrict__ dwb, const float* __restrict__ lnw,
    const float* __restrict__ lnb, const float* __restrict__ pww,
    float* __restrict__ pos) {
  __shared__ float qg[4 * 64 * 64];   // [g][c][s^swz]  (64 KB)
  int b = blockIdx.x;
  int tid = threadIdx.x;
  int g = tid >> 6;
  int t = tid & 63;
  const float* qgrp = q + (size_t)b * 16384 + g * 4096;
  float* qs = qg + g * 4096;
  for (int c = 0; c < 64; ++c)
    qs[c * 64 + (t ^ (c & 31))] = qgrp[c * 64 + t];   // coalesced global read
  __syncthreads();

  // depthwise 3x3, stride 2, pad 1 -> 4x4; thread t = channel
  float w9[9];
#pragma unroll
  for (int k = 0; k < 9; ++k) w9[k] = dww[t * 9 + k];
  float cb = dwb[t];
  const float* qr = qs + t * 64;
  int sw = t & 31;
  float val[16];
#pragma unroll
  for (int i = 0; i < 4; ++i)
#pragma unroll
    for (int j = 0; j < 4; ++j) {
      float s = cb;
#pragma unroll
      for (int ky = 0; ky < 3; ++ky) {
        int yy = 2 * i - 1 + ky;
        if (yy < 0 || yy > 7) continue;
#pragma unroll
        for (int kx = 0; kx < 3; ++kx) {
          int xx = 2 * j - 1 + kx;
          if (xx < 0 || xx > 7) continue;
          s += w9[ky * 3 + kx] * qr[(yy * 8 + xx) ^ sw];
        }
      }
      val[i * 4 + j] = s;
    }

  float lw = lnw[t], lb = lnb[t];
  float pwy = pww[t], pwx = pww[64 + t];
  float oy = 0.f, ox = 0.f;
#pragma unroll
  for (int s = 0; s < 16; ++s) {
    float v = val[s];
    float sum = v, sq = v * v;
#pragma unroll
    for (int m = 1; m < 64; m <<= 1) {
      sum += __shfl_xor(sum, m, 64);
      sq  += __shfl_xor(sq, m, 64);
    }
    float mu = sum * 0.015625f;
    float var = sq * 0.015625f - mu * mu;
    float rs = rsqrtf(var + 1e-5f);
    float h = (v - mu) * rs * lw + lb;
    h = 0.5f * h * (1.0f + erff(h * 0.70710678118654752f));  // exact GELU
    float sy = h * pwy, sx = h * pwx;
#pragma unroll
    for (int m = 1; m < 64; m <<= 1) {
      sy += __shfl_xor(sy, m, 64);
      sx += __shfl_xor(sx, m, 64);
    }
    if (t == s) { oy = sy; ox = sx; }
  }
  if (t < 16) {
    int i = t >> 2, j = t & 3;
    float py = tanhf(oy) * (2.0f / 3.0f) + (-0.75f + 0.5f * (float)i);
    float px = tanhf(ox) * (2.0f / 3.0f) + (-0.75f + 0.5f * (float)j);
    float* pp = pos + ((size_t)b * 4 + g) * 32 + t * 2;
    pp[0] = py; pp[1] = px;
  }
}

// ---------------- K3: fused sample -> k,v -> attn -> per-head-fold y ---------
// LDS regions (floats, stride-16 rows, all row reads aligned b128):
//   POS 0..128, RPE 128..2048 ([8][15][16]),
//   R1 2048 (xs; later P rows 0..255), R2 6144 (k; later P rows 256..511),
//   R3 10240 (v — live until phase E)
#define SM_POS 0
#define SM_RPE 128
#define SM_R1  2048
#define SM_R2  6144
#define SM_R3  10240

__global__ __launch_bounds__(256) void k_attn(
    const float* __restrict__ x, const float* __restrict__ q,
    const float* __restrict__ wkT, const float* __restrict__ bk,
    const float* __restrict__ wvT, const float* __restrict__ bv,
    const float* __restrict__ woT, const float* __restrict__ bo,
    const float* __restrict__ rpe, const float* __restrict__ pos,
    float* __restrict__ y) {
  __shared__ float sm[14336];   // 57,344 B
  int b = blockIdx.x;
  int tid = threadIdx.x;
  const float* xb = x + (size_t)b * 16384;
  const float* qb = q + (size_t)b * 16384;
  float* yb = y + (size_t)b * 16384;

  if (tid < 128) sm[SM_POS + tid] = pos[(size_t)b * 128 + tid];
  for (int i = tid; i < 1800; i += 256) {     // rpe_table (8,15,15) -> padded rows
    int h = i / 225;
    int rem = i - h * 225;
    int yy = rem / 15;
    int xx = rem - yy * 15;
    sm[SM_RPE + h * 240 + yy * 16 + xx] = rpe[i];
  }
  __syncthreads();

  // ---- Phase B: bilinear sample (align_corners=True, zeros pad) -> xs
  {
    int g = tid >> 6, cc = tid & 63;
    int ch = (g << 6) + cc;                  // wave == group -> coalesced x reads
    for (int n = 0; n < 16; ++n) {
      float py = sm[SM_POS + g * 32 + 2 * n];
      float px = sm[SM_POS + g * 32 + 2 * n + 1];
      float gx = (px + 1.0f) * 3.5f;         // (x+1)/2*(W-1)
      float gy = (py + 1.0f) * 3.5f;
      float x0 = floorf(gx), y0 = floorf(gy);
      float wx1 = gx - x0, wy1 = gy - y0;
      float acc = 0.0f;
#pragma unroll
      for (int dy = 0; dy < 2; ++dy)
#pragma unroll
        for (int dx = 0; dx < 2; ++dx) {
          float fx = x0 + dx, fy = y0 + dy;
          float w = (dx ? wx1 : 1.0f - wx1) * (dy ? wy1 : 1.0f - wy1);
          bool valid = (fx >= 0.0f) & (fx <= 7.0f) & (fy >= 0.0f) & (fy <= 7.0f);
          int ix = (int)fminf(fmaxf(fx, 0.0f), 7.0f);
          int iy = (int)fminf(fmaxf(fy, 0.0f), 7.0f);
          float vv = xb[(iy * 8 + ix) * 256 + ch];
          acc += valid ? (w * vv) : 0.0f;
        }
      sm[SM_R1 + ch * 16 + n] = acc;
    }
  }
  __syncthreads();

  // ---- Phase C: k = Wk.xs + bk, v = Wv.xs + bv  (thread = channel d)
  {
    int d = tid;
    float ka[16], va[16];
    float bkv = bk[d], bvv = bv[d];
#pragma unroll
    for (int n = 0; n < 16; ++n) { ka[n] = bkv; va[n] = bvv; }
    for (int c = 0; c < 256; ++c) {
      float wkc = wkT[c * 256 + d];
      float wvc = wvT[c * 256 + d];
      F4 xr[4];
#pragma unroll
      for (int i = 0; i < 4; ++i) xr[i].v = *(const float4*)&sm[SM_R1 + c * 16 + 4 * i];
#pragma unroll
      for (int n = 0; n < 16; ++n) {
        float xv = xr[n >> 2].f[n & 3];
        ka[n] += wkc * xv;
        va[n] += wvc * xv;
      }
    }
    __syncthreads();   // xs reads done; k overwrites R2, v -> R3
#pragma unroll
    for (int i = 0; i < 4; ++i) {
      F4 kk, vv;
#pragma unroll
      for (int e = 0; e < 4; ++e) { kk.f[e] = ka[4 * i + e]; vv.f[e] = va[4 * i + e]; }
      *(float4*)&sm[SM_R2 + d * 16 + 4 * i] = kk.v;
      *(float4*)&sm[SM_R3 + d * 16 + 4 * i] = vv.v;
    }
  }
  __syncthreads();

  // ---- Phase D: logits = q.k/sqrt(32) + rpe_bias; softmax over 16 -> P
  // P row (h*64+m) written at SM_R1 + row*16 (spans R1+R2; xs and k dead).
  {
    float lg[2][16];
#pragma unroll
    for (int rep = 0; rep < 2; ++rep) {
      int row = tid + (rep << 8);            // (h,m), h uniform per wave
      int h = row >> 6, m = row & 63, g = h >> 1;
#pragma unroll
      for (int n = 0; n < 16; ++n) lg[rep][n] = 0.f;
      for (int c = 0; c < 32; ++c) {
        float qv = qb[(h * 32 + c) * 64 + m];
        F4 kr[4];
#pragma unroll
        for (int i = 0; i < 4; ++i)
          kr[i].v = *(const float4*)&sm[SM_R2 + (h * 32 + c) * 16 + 4 * i];
#pragma unroll
        for (int n = 0; n < 16; ++n)
          lg[rep][n] += qv * kr[n >> 2].f[n & 3];
      }
      float qy = -0.9375f + 0.25f * (float)(m >> 3);
      float qx = -0.9375f + 0.25f * (float)(m & 7);
      const float* rp = &sm[SM_RPE + h * 240];
#pragma unroll
      for (int n = 0; n < 16; ++n) {
        float py = sm[SM_POS + g * 32 + 2 * n];
        float px = sm[SM_POS + g * 32 + 2 * n + 1];
        float dxx = (qx - px) * 0.5f, dyy = (qy - py) * 0.5f;
        float gx = (dxx + 1.0f) * 7.0f;      // (x+1)/2*(15-1)
        float gy = (dyy + 1.0f) * 7.0f;
        float x0 = floorf(gx), y0 = floorf(gy);
        float wx1 = gx - x0, wy1 = gy - y0;
        float bias = 0.f;
#pragma unroll
        for (int dy = 0; dy < 2; ++dy)
#pragma unroll
          for (int dx = 0; dx < 2; ++dx) {
            float fx = x0 + dx, fy = y0 + dy;
            float w = (dx ? wx1 : 1.0f - wx1) * (dy ? wy1 : 1.0f - wy1);
            bool valid = (fx >= 0.0f) & (fx <= 14.0f) & (fy >= 0.0f) & (fy <= 14.0f);
            int ix = (int)fminf(fmaxf(fx, 0.0f), 14.0f);
            int iy = (int)fminf(fmaxf(fy, 0.0f), 14.0f);
            float vv = rp[iy * 16 + ix];
            bias += valid ? (w * vv) : 0.0f;
          }
        lg[rep][n] = lg[rep][n] * 0.17677669529663687f + bias;
      }
    }
    __syncthreads();   // all k reads done before P overwrites R1+R2
#pragma unroll
    for (int rep = 0; rep < 2; ++rep) {
      int row = tid + (rep << 8);
      float mx = lg[rep][0];
#pragma unroll
      for (int n = 1; n < 16; ++n) mx = fmaxf(mx, lg[rep][n]);
      float ssum = 0.f;
      float pe[16];
#pragma unroll
      for (int n = 0; n < 16; ++n) { pe[n] = expf(lg[rep][n] - mx); ssum += pe[n]; }
      float inv = 1.0f / ssum;
#pragma unroll
      for (int i = 0; i < 4; ++i) {
        F4 pp;
#pragma unroll
        for (int e = 0; e < 4; ++e) pp.f[e] = pe[4 * i + e] * inv;
        *(float4*)&sm[SM_R1 + row * 16 + 4 * i] = pp.v;
      }
    }
  }
  __syncthreads();

  // ---- Phase E: per-head fold.  thread = output channel d.
  //   voh[h][n] = sum_{c in head h} wo[d][c] * v[c][n]      (v in R3)
  //   y[d][m]   = bo[d] + sum_h sum_n P[(h*64+m)][n] * voh[h][n]
  {
    int d = tid;
    float voh[8][16];
#pragma unroll
    for (int h = 0; h < 8; ++h) {
#pragma unroll
      for (int n = 0; n < 16; ++n) voh[h][n] = 0.f;
      for (int c = h * 32; c < h * 32 + 32; ++c) {
        float woc = woT[c * 256 + d];
        F4 vr[4];
#pragma unroll
        for (int i = 0; i < 4; ++i) vr[i].v = *(const float4*)&sm[SM_R3 + c * 16 + 4 * i];
#pragma unroll
        for (int n = 0; n < 16; ++n)
          voh[h][n] += woc * vr[n >> 2].f[n & 3];
      }
    }
    float bov = bo[d];
    for (int m0 = 0; m0 < 64; m0 += 4) {
      F4 o;
#pragma unroll
      for (int mm = 0; mm < 4; ++mm) {
        int m = m0 + mm;
        float acc = bov;
#pragma unroll
        for (int h = 0; h < 8; ++h) {
          F4 pr[4];
#pragma unroll
          for (int i = 0; i < 4; ++i)
            pr[i].v = *(const float4*)&sm[SM_R1 + (h * 64 + m) * 16 + 4 * i];
#pragma unroll
          for (int n = 0; n < 16; ++n)
            acc += voh[h][n] * pr[n >> 2].f[n & 3];
        }
        o.f[mm] = acc;
      }
      *(float4*)(yb + d * 64 + m0) = o.v;
    }
  }
}

extern "C" void kernel_launch(void* const* d_in, const int* in_sizes, int n_in,
                              void* d_out, int out_size, void* d_ws, size_t ws_size,
                              hipStream_t stream) {
  const float* x   = (const float*)d_in[0];
  const float* wq  = (const float*)d_in[1];
  const float* bq  = (const float*)d_in[2];
  const float* wk  = (const float*)d_in[3];
  const float* bk  = (const float*)d_in[4];
  const float* wv  = (const float*)d_in[5];
  const float* bv  = (const float*)d_in[6];
  const float* wo  = (const float*)d_in[7];
  const float* bo  = (const float*)d_in[8];
  const float* dww = (const float*)d_in[9];
  const float* dwb = (const float*)d_in[10];
  const float* lnw = (const float*)d_in[11];
  const float* lnb = (const float*)d_in[12];
  const float* pww = (const float*)d_in[13];
  const float* rpe = (const float*)d_in[14];

  float* ws  = (float*)d_ws;
  float* wqT = ws;
  float* wkT = ws + 65536;
  float* wvT = ws + 131072;
  float* woT = ws + 196608;
  float* q   = ws + 262144;                 // 67,108,864 floats
  float* pos = ws + 67371008;               // 524,288 floats
  float* y   = (float*)d_out;

  k_transpose4<<<1024, 256, 0, stream>>>(wq, wk, wv, wo, wqT, wkT, wvT, woT);
  k_qproj   <<<4096, 256, 0, stream>>>(x, wqT, bq, q);
  k_offset  <<<4096, 256, 0, stream>>>(q, dww, dwb, lnw, lnb, pww, pos);
  k_attn    <<<4096, 256, 0, stream>>>(x, q, wkT, bk, wvT, bv, woT, bo, rpe, pos, y);
}